// Round 3
// baseline (629.252 us; speedup 1.0000x reference)
//
#include <hip/hip_runtime.h>
#include <hip/hip_bf16.h>

#define NB   32
#define C    256
#define CI   128
#define HW   4096
#define FNHW 131072.0f

typedef __attribute__((ext_vector_type(8))) short short8;
typedef __attribute__((ext_vector_type(4))) float floatx4;

__device__ __forceinline__ unsigned short f2bf(float f) {
    unsigned int u = __float_as_uint(f);
    return (unsigned short)((u + 0x7fffu + ((u >> 16) & 1u)) >> 16);
}

// ---------------------------------------------------------------------------
// K0: x fp32 [n][c][t] -> xb16 (same layout, bf16), xT bf16 [n][t][c],
// plus per-(n,c) channel sums s (atomic). grid (64,4,32), block 256.
__global__ __launch_bounds__(256) void k_prep(const float* __restrict__ x,
        unsigned short* __restrict__ xb16, unsigned short* __restrict__ xT,
        float* __restrict__ s) {
    const int n = blockIdx.z, c0 = blockIdx.y * 64, t0 = blockIdx.x * 64;
    __shared__ float sA[64][68];
    const int tid = threadIdx.x;
    const int cr = tid >> 4;          // 0..15
    const int tq = (tid & 15) * 4;    // 0..60
#pragma unroll
    for (int pass = 0; pass < 4; ++pass) {
        const int c = cr + pass * 16;
        const float4 v = *(const float4*)&x[((size_t)n * C + c0 + c) * HW + t0 + tq];
        // straight-layout bf16 copy (for Gram GEMM)
        uint2 u2;
        u2.x = (unsigned int)f2bf(v.x) | ((unsigned int)f2bf(v.y) << 16);
        u2.y = (unsigned int)f2bf(v.z) | ((unsigned int)f2bf(v.w) << 16);
        *(uint2*)&xb16[((size_t)n * C + c0 + c) * HW + t0 + tq] = u2;
        const int swz = ((c >> 3) & 7) * 8;
        *(float4*)&sA[c][tq ^ swz] = v;
        float ps = v.x + v.y + v.z + v.w;
        for (int off = 1; off < 16; off <<= 1) ps += __shfl_xor(ps, off, 64);
        if ((tid & 15) == 0) atomicAdd(&s[n * C + c0 + c], ps);
    }
    __syncthreads();
    const int tr = tid >> 3;          // 0..31
    const int cc = (tid & 7) * 8;     // 0..56
#pragma unroll
    for (int pass = 0; pass < 2; ++pass) {
        const int t = tr + pass * 32;
        unsigned int w[4];
#pragma unroll
        for (int jj = 0; jj < 4; ++jj) {
            const int ca = cc + 2 * jj, cb = cc + 2 * jj + 1;
            unsigned short lo = f2bf(sA[ca][t ^ (((ca >> 3) & 7) * 8)]);
            unsigned short hi = f2bf(sA[cb][t ^ (((cb >> 3) & 7) * 8)]);
            w[jj] = (unsigned int)lo | ((unsigned int)hi << 16);
        }
        uint4 u4; u4.x = w[0]; u4.y = w[1]; u4.z = w[2]; u4.w = w[3];
        *(uint4*)&xT[((size_t)n * HW + t0 + t) * C + c0 + cc] = u4;
    }
}

// ---------------------------------------------------------------------------
// K1: Gram G_n = x_n x_n^T (bf16 out). grid (4, NB), block 256 (4 waves, 2x2).
__global__ __launch_bounds__(256) void k_gram(const unsigned short* __restrict__ xb16,
        unsigned short* __restrict__ Gb16) {
    const int tile = blockIdx.x, n = blockIdx.y;
    const int rt = (tile >> 1) * 128, ct = (tile & 1) * 128;
    const int wave = threadIdx.x >> 6, lane = threadIdx.x & 63;
    const int wm = (wave >> 1) * 64, wn = (wave & 1) * 64;
    const int l15 = lane & 15, q8 = (lane >> 4) * 8;
    const unsigned short* Abase = xb16 + ((size_t)n * C + rt + wm + l15) * HW + q8;
    const unsigned short* Bbase = xb16 + ((size_t)n * C + ct + wn + l15) * HW + q8;
    floatx4 acc[4][4] = {};
    for (int k0 = 0; k0 < HW; k0 += 32) {
        short8 a[4], b[4];
#pragma unroll
        for (int i = 0; i < 4; ++i)
            a[i] = *(const short8*)(Abase + (size_t)i * 16 * HW + k0);
#pragma unroll
        for (int j = 0; j < 4; ++j)
            b[j] = *(const short8*)(Bbase + (size_t)j * 16 * HW + k0);
#pragma unroll
        for (int i = 0; i < 4; ++i)
#pragma unroll
            for (int j = 0; j < 4; ++j)
                acc[i][j] = __builtin_amdgcn_mfma_f32_16x16x32_bf16(
                    a[i], b[j], acc[i][j], 0, 0, 0);
    }
    const int quad = lane >> 4;
#pragma unroll
    for (int i = 0; i < 4; ++i) {
        const int row = rt + wm + i * 16 + quad * 4;
#pragma unroll
        for (int r = 0; r < 4; ++r)
#pragma unroll
            for (int j = 0; j < 4; ++j)
                Gb16[((size_t)n * C + row + r) * C + ct + wn + j * 16 + l15] =
                    f2bf(acc[i][j][r]);
    }
}

// ---------------------------------------------------------------------------
// K2: theta/phi vectors per batch + ph max/min. grid 32, block 128.
__global__ __launch_bounds__(128) void k_thph(const float* __restrict__ s,
        const float* __restrict__ w_theta, const float* __restrict__ b_theta,
        const float* __restrict__ w_phi,  const float* __restrict__ b_phi,
        float* __restrict__ th, float* __restrict__ ph, float* __restrict__ pm) {
    const int n = blockIdx.x, d = threadIdx.x;
    __shared__ float sh_s[C];
    __shared__ float smax[2], smin[2];
    sh_s[d]       = s[n * C + d];
    sh_s[d + 128] = s[n * C + d + 128];
    __syncthreads();
    float td = 0.f, pd = 0.f;
    for (int c = 0; c < C; ++c) {
        const float sv = sh_s[c] * (1.f / 16.f);
        td += w_theta[d * C + c] * sv;
        pd += w_phi[d * C + c] * sv;
    }
    td = (td + 256.f * b_theta[d]) * 0.08838834764831845f;
    pd = pd + 256.f * b_phi[d];
    th[n * CI + d] = td;
    ph[n * CI + d] = pd;
    float pmax = pd, pmin = pd;
    for (int off = 32; off; off >>= 1) {
        pmax = fmaxf(pmax, __shfl_xor(pmax, off, 64));
        pmin = fminf(pmin, __shfl_xor(pmin, off, 64));
    }
    if ((d & 63) == 0) { smax[d >> 6] = pmax; smin[d >> 6] = pmin; }
    __syncthreads();
    if (d == 0) {
        pm[n * 2 + 0] = fmaxf(smax[0], smax[1]);
        pm[n * 2 + 1] = fminf(smin[0], smin[1]);
    }
}

// ---------------------------------------------------------------------------
// K3: one softmax row of A per wave. grid NB*CI, block 64.
__global__ __launch_bounds__(64) void k_arow(const float* __restrict__ th,
        const float* __restrict__ ph, const float* __restrict__ pm,
        const float* __restrict__ b_g,
        float* __restrict__ A, float* __restrict__ q) {
    const int n = blockIdx.x >> 7, c = blockIdx.x & 127, lane = threadIdx.x;
    const float thc = th[n * CI + c];
    const float2 phv = *(const float2*)&ph[n * CI + lane * 2];
    const float m = (thc >= 0.f) ? thc * pm[n * 2] : thc * pm[n * 2 + 1];
    float e0 = __expf(thc * phv.x - m);
    float e1 = __expf(thc * phv.y - m);
    float z = e0 + e1;
    for (int off = 32; off; off >>= 1) z += __shfl_xor(z, off, 64);
    const float inv = 1.f / z;
    e0 *= inv; e1 *= inv;
    float2 av; av.x = e0; av.y = e1;
    *(float2*)&A[((size_t)n * CI + c) * CI + lane * 2] = av;
    const float2 bg = *(const float2*)&b_g[lane * 2];
    float qv = e0 * bg.x + e1 * bg.y;
    for (int off = 32; off; off >>= 1) qv += __shfl_xor(qv, off, 64);
    if (lane == 0) q[n * CI + c] = qv;
}

// ---------------------------------------------------------------------------
// K4: W_n[o,d] = sum_c w_out[o,c] A_n[c,d]; 8 o's per block via uniform loads.
// grid NB*32, block 128 (d). Also cvec[n,o] = w_out[o,:].q_n + b_out[o].
__global__ __launch_bounds__(128) void k_W(const float* __restrict__ w_out,
        const float* __restrict__ A, const float* __restrict__ q,
        const float* __restrict__ b_out,
        float* __restrict__ W, float* __restrict__ cvec) {
    const int n = blockIdx.x >> 5, o0 = (blockIdx.x & 31) * 8, d = threadIdx.x;
    const float* Ab = A + (size_t)n * CI * CI + d;
    float acc[8] = {};
    for (int c = 0; c < CI; ++c) {
        const float av = Ab[(size_t)c * CI];
#pragma unroll
        for (int o = 0; o < 8; ++o) acc[o] += w_out[(o0 + o) * CI + c] * av;
    }
#pragma unroll
    for (int o = 0; o < 8; ++o) W[((size_t)n * C + o0 + o) * CI + d] = acc[o];
    // cvec: 8 dots of length 128 reduced across the 2 waves
    __shared__ float red[8][2];
    const float qv = q[n * CI + d];
#pragma unroll
    for (int o = 0; o < 8; ++o) {
        float p = w_out[(o0 + o) * CI + d] * qv;
        for (int off = 32; off; off >>= 1) p += __shfl_down(p, off, 64);
        if ((d & 63) == 0) red[o][d >> 6] = p;
    }
    __syncthreads();
    if (d < 8) cvec[n * C + o0 + d] = red[d][0] + red[d][1] + b_out[o0 + d];
}

// ---------------------------------------------------------------------------
// K5: M_n[o,c2] = sum_d W_n[o,d] w_g[d,c2]; 8 o's per block, uniform W loads.
// grid NB*32, block 256 (c2). Writes fp32 M and bf16 Mb16.
__global__ __launch_bounds__(256) void k_M(const float* __restrict__ W,
        const float* __restrict__ w_g, float* __restrict__ M,
        unsigned short* __restrict__ Mb16) {
    const int n = blockIdx.x >> 5, o0 = (blockIdx.x & 31) * 8, c2 = threadIdx.x;
    float acc[8] = {};
    for (int d = 0; d < CI; ++d) {
        const float wv = w_g[d * C + c2];
#pragma unroll
        for (int o = 0; o < 8; ++o)
            acc[o] += W[((size_t)n * C + o0 + o) * CI + d] * wv;
    }
#pragma unroll
    for (int o = 0; o < 8; ++o) {
        M[((size_t)n * C + o0 + o) * C + c2] = acc[o];
        Mb16[((size_t)n * C + o0 + o) * C + c2] = f2bf(acc[o]);
    }
}

// ---------------------------------------------------------------------------
// K6: linear BN terms: mean_acc[o] += m.s_n + HW*cv; e2_acc[o] += 2cv(m.s_n)+HW*cv^2
// grid NB*C, block 64.
__global__ __launch_bounds__(64) void k_bnpre(const float* __restrict__ M,
        const float* __restrict__ s, const float* __restrict__ cvec,
        float* __restrict__ mean_acc, float* __restrict__ e2_acc) {
    const int n = blockIdx.x >> 8, o = blockIdx.x & 255, lane = threadIdx.x;
    const float4 mv = *(const float4*)&M[((size_t)n * C + o) * C + lane * 4];
    const float4 sv = *(const float4*)&s[n * C + lane * 4];
    float d1 = mv.x * sv.x + mv.y * sv.y + mv.z * sv.z + mv.w * sv.w;
    for (int off = 32; off; off >>= 1) d1 += __shfl_xor(d1, off, 64);
    if (lane == 0) {
        const float cv = cvec[n * C + o];
        atomicAdd(&mean_acc[o], d1 + 4096.f * cv);
        atomicAdd(&e2_acc[o], 2.f * cv * d1 + 4096.f * cv * cv);
    }
}

// ---------------------------------------------------------------------------
// K7: quadratic forms via MFMA: T = G_n . m_o, then qf[o] = sum_c m_o[c] T[c,o]
// accumulated straight into e2_acc. grid (4, NB), block 256.
__global__ __launch_bounds__(256) void k_quad(const unsigned short* __restrict__ Gb16,
        const unsigned short* __restrict__ Mb16, const float* __restrict__ M,
        float* __restrict__ e2_acc) {
    const int tile = blockIdx.x, n = blockIdx.y;
    const int rt = (tile >> 1) * 128, ot = (tile & 1) * 128;
    const int wave = threadIdx.x >> 6, lane = threadIdx.x & 63;
    const int wm = (wave >> 1) * 64, wn = (wave & 1) * 64;
    const int l15 = lane & 15, q8 = (lane >> 4) * 8;
    const unsigned short* Abase = Gb16 + ((size_t)n * C + rt + wm + l15) * C + q8;
    const unsigned short* Bbase = Mb16 + ((size_t)n * C + ot + wn + l15) * C + q8;
    floatx4 acc[4][4] = {};
    for (int k0 = 0; k0 < C; k0 += 32) {
        short8 a[4], b[4];
#pragma unroll
        for (int i = 0; i < 4; ++i)
            a[i] = *(const short8*)(Abase + (size_t)i * 16 * C + k0);
#pragma unroll
        for (int j = 0; j < 4; ++j)
            b[j] = *(const short8*)(Bbase + (size_t)j * 16 * C + k0);
#pragma unroll
        for (int i = 0; i < 4; ++i)
#pragma unroll
            for (int j = 0; j < 4; ++j)
                acc[i][j] = __builtin_amdgcn_mfma_f32_16x16x32_bf16(
                    a[i], b[j], acc[i][j], 0, 0, 0);
    }
    const int quad = lane >> 4;
#pragma unroll
    for (int j = 0; j < 4; ++j) {
        const int o = ot + wn + j * 16 + l15;
        float pj = 0.f;
#pragma unroll
        for (int i = 0; i < 4; ++i) {
            const int c = rt + wm + i * 16 + quad * 4;
            const float4 m4 = *(const float4*)&M[((size_t)n * C + o) * C + c];
            pj += acc[i][j][0] * m4.x + acc[i][j][1] * m4.y +
                  acc[i][j][2] * m4.z + acc[i][j][3] * m4.w;
        }
        pj += __shfl_xor(pj, 16, 64);
        pj += __shfl_xor(pj, 32, 64);
        if (quad == 0) atomicAdd(&e2_acc[o], pj);
    }
}

// ---------------------------------------------------------------------------
// K8: finalize scale/shift. 1 block, 256 threads.
__global__ __launch_bounds__(256) void k_bnfin(const float* __restrict__ mean_acc,
        const float* __restrict__ e2_acc, const float* __restrict__ gamma,
        const float* __restrict__ beta,
        float* __restrict__ scale, float* __restrict__ shift) {
    const int o = threadIdx.x;
    const float mean = mean_acc[o] * (1.f / FNHW);
    const float e2   = e2_acc[o] * (1.f / FNHW);
    const float var  = e2 - mean * mean;
    const float sc   = gamma[o] * rsqrtf(var + 1e-5f);
    scale[o] = sc;
    shift[o] = beta[o] - mean * sc;
}

// ---------------------------------------------------------------------------
// K9: fused main GEMM + BN + residual: out = x + sc*(M@x + cv) + sh.
// grid (64, NB), block 256 (4 waves 2x2 of 64x64).
__global__ __launch_bounds__(256) void k_gemm_fused(
        const unsigned short* __restrict__ xT, const unsigned short* __restrict__ Mb,
        const float* __restrict__ cvec, const float* __restrict__ x,
        const float* __restrict__ scale, const float* __restrict__ shift,
        float* __restrict__ out) {
    const int n  = blockIdx.y;
    const int tt = (blockIdx.x & 31) * 128;
    const int ot = (blockIdx.x >> 5) * 128;
    const int wave = threadIdx.x >> 6, lane = threadIdx.x & 63;
    const int wm = (wave >> 1) * 64, wn = (wave & 1) * 64;
    const int l15 = lane & 15, q8 = (lane >> 4) * 8;
    const unsigned short* Abase = Mb + ((size_t)n * C + ot + wm + l15) * C + q8;
    const unsigned short* Bbase = xT + ((size_t)n * HW + tt + wn + l15) * C + q8;
    floatx4 acc[4][4] = {};
    for (int k0 = 0; k0 < C; k0 += 32) {
        short8 a[4], b[4];
#pragma unroll
        for (int i = 0; i < 4; ++i)
            a[i] = *(const short8*)(Abase + (size_t)i * 16 * C + k0);
#pragma unroll
        for (int j = 0; j < 4; ++j)
            b[j] = *(const short8*)(Bbase + (size_t)j * 16 * C + k0);
#pragma unroll
        for (int i = 0; i < 4; ++i)
#pragma unroll
            for (int j = 0; j < 4; ++j)
                acc[i][j] = __builtin_amdgcn_mfma_f32_16x16x32_bf16(
                    a[i], b[j], acc[i][j], 0, 0, 0);
    }
    const int quad = lane >> 4;
#pragma unroll
    for (int i = 0; i < 4; ++i) {
        const int rowb = ot + wm + i * 16 + quad * 4;
#pragma unroll
        for (int r = 0; r < 4; ++r) {
            const int row = rowb + r;
            const float cv = cvec[n * C + row];
            const float sc = scale[row], sh = shift[row];
            const float* xrow = x + ((size_t)n * C + row) * HW + tt + wn + l15;
            float* orow = out + ((size_t)n * C + row) * HW + tt + wn + l15;
#pragma unroll
            for (int j = 0; j < 4; ++j)
                orow[j * 16] = xrow[j * 16] + sc * (acc[i][j][r] + cv) + sh;
        }
    }
}

// ---------------------------------------------------------------------------
extern "C" void kernel_launch(void* const* d_in, const int* in_sizes, int n_in,
                              void* d_out, int out_size, void* d_ws, size_t ws_size,
                              hipStream_t stream) {
    const float* x       = (const float*)d_in[0];
    const float* w_theta = (const float*)d_in[1];
    const float* b_theta = (const float*)d_in[2];
    const float* w_phi   = (const float*)d_in[3];
    const float* b_phi   = (const float*)d_in[4];
    const float* w_g     = (const float*)d_in[5];
    const float* b_g     = (const float*)d_in[6];
    const float* w_out   = (const float*)d_in[7];
    const float* b_out   = (const float*)d_in[8];
    const float* gamma   = (const float*)d_in[9];
    const float* beta    = (const float*)d_in[10];
    float* out = (float*)d_out;
    float* ws  = (float*)d_ws;

    // workspace layout (float offsets)
    float* s        = ws;                        // 8192
    float* mean_acc = s + NB * C;                // 256
    float* e2_acc   = mean_acc + C;              // 256  (zero region ends here)
    float* th       = e2_acc + C;                // 4096
    float* ph       = th + NB * CI;              // 4096
    float* pm       = ph + NB * CI;              // 64
    float* A        = pm + NB * 2;               // 524288
    float* q        = A + (size_t)NB * CI * CI;  // 4096
    float* W        = q + NB * CI;               // 1048576
    float* M        = W + (size_t)NB * C * CI;   // 2097152
    float* cvec     = M + (size_t)NB * C * C;    // 8192
    float* scale    = cvec + NB * C;             // 256
    float* shift    = scale + C;                 // 256
    unsigned short* Mb16 = (unsigned short*)(shift + C);
    unsigned short* Gb16 = Mb16 + (size_t)NB * C * C;
    unsigned short* xb16 = Gb16 + (size_t)NB * C * C;
    unsigned short* xT   = xb16 + (size_t)NB * C * HW;

    hipMemsetAsync(s, 0, (NB * C + 2 * C) * sizeof(float), stream);
    k_prep<<<dim3(64, 4, NB), 256, 0, stream>>>(x, xb16, xT, s);
    k_gram<<<dim3(4, NB), 256, 0, stream>>>(xb16, Gb16);
    k_thph<<<NB, CI, 0, stream>>>(s, w_theta, b_theta, w_phi, b_phi, th, ph, pm);
    k_arow<<<NB * CI, 64, 0, stream>>>(th, ph, pm, b_g, A, q);
    k_W<<<NB * 32, CI, 0, stream>>>(w_out, A, q, b_out, W, cvec);
    k_M<<<NB * 32, C, 0, stream>>>(W, w_g, M, Mb16);
    k_bnpre<<<NB * C, 64, 0, stream>>>(M, s, cvec, mean_acc, e2_acc);
    k_quad<<<dim3(4, NB), 256, 0, stream>>>(Gb16, Mb16, M, e2_acc);
    k_bnfin<<<1, C, 0, stream>>>(mean_acc, e2_acc, gamma, beta, scale, shift);
    k_gemm_fused<<<dim3(64, NB), 256, 0, stream>>>(xT, Mb16, cvec, x, scale, shift, out);
}

// Round 4
// 577.645 us; speedup vs baseline: 1.0893x; 1.0893x over previous
//
#include <hip/hip_runtime.h>
#include <hip/hip_bf16.h>

#define NB   32
#define C    256
#define CI   128
#define HW   4096
#define FNHW 131072.0f

typedef __attribute__((ext_vector_type(8))) short short8;
typedef __attribute__((ext_vector_type(4))) float floatx4;

__device__ __forceinline__ unsigned short f2bf(float f) {
    unsigned int u = __float_as_uint(f);
    return (unsigned short)((u + 0x7fffu + ((u >> 16) & 1u)) >> 16);
}

// ---------------------------------------------------------------------------
// K0: x fp32 [n][c][t] -> xT bf16 [n][t][c] + per-(n,c) channel sums s.
// grid (64,4,32), block 256.  (verified round 2)
__global__ __launch_bounds__(256) void k_prep(const float* __restrict__ x,
        unsigned short* __restrict__ xT, float* __restrict__ s) {
    const int n = blockIdx.z, c0 = blockIdx.y * 64, t0 = blockIdx.x * 64;
    __shared__ float sA[64][68];
    const int tid = threadIdx.x;
    const int cr = tid >> 4;          // 0..15
    const int tq = (tid & 15) * 4;    // 0..60
#pragma unroll
    for (int pass = 0; pass < 4; ++pass) {
        const int c = cr + pass * 16;
        const float4 v = *(const float4*)&x[((size_t)n * C + c0 + c) * HW + t0 + tq];
        const int swz = ((c >> 3) & 7) * 8;
        *(float4*)&sA[c][tq ^ swz] = v;
        float ps = v.x + v.y + v.z + v.w;
        for (int off = 1; off < 16; off <<= 1) ps += __shfl_xor(ps, off, 64);
        if ((tid & 15) == 0) atomicAdd(&s[n * C + c0 + c], ps);
    }
    __syncthreads();
    const int tr = tid >> 3;          // 0..31
    const int cc = (tid & 7) * 8;     // 0..56
#pragma unroll
    for (int pass = 0; pass < 2; ++pass) {
        const int t = tr + pass * 32;
        unsigned int w[4];
#pragma unroll
        for (int jj = 0; jj < 4; ++jj) {
            const int ca = cc + 2 * jj, cb = cc + 2 * jj + 1;
            unsigned short lo = f2bf(sA[ca][t ^ (((ca >> 3) & 7) * 8)]);
            unsigned short hi = f2bf(sA[cb][t ^ (((cb >> 3) & 7) * 8)]);
            w[jj] = (unsigned int)lo | ((unsigned int)hi << 16);
        }
        uint4 u4; u4.x = w[0]; u4.y = w[1]; u4.z = w[2]; u4.w = w[3];
        *(uint4*)&xT[((size_t)n * HW + t0 + t) * C + c0 + cc] = u4;
    }
}

// ---------------------------------------------------------------------------
// K1: fused theta/phi + softmax rows + q.  grid (8, NB), block 128.
// Each block recomputes th/ph for its n (cheap, L2-resident weights), then
// wave w handles 8 softmax rows: c = part*16 + w*8 + cc.
__global__ __launch_bounds__(128) void k_attn(const float* __restrict__ s,
        const float* __restrict__ w_theta, const float* __restrict__ b_theta,
        const float* __restrict__ w_phi,  const float* __restrict__ b_phi,
        const float* __restrict__ b_g,
        float* __restrict__ A, float* __restrict__ q) {
    const int part = blockIdx.x, n = blockIdx.y;
    const int tid = threadIdx.x;
    __shared__ float sh_s[C], th_s[CI], ph_s[CI], red2[4];

    sh_s[tid]       = s[n * C + tid];
    sh_s[tid + 128] = s[n * C + tid + 128];
    __syncthreads();

    float td = 0.f, pd = 0.f;
    for (int c = 0; c < C; ++c) {
        const float sv = sh_s[c] * (1.f / 16.f);
        td += w_theta[tid * C + c] * sv;
        pd += w_phi[tid * C + c] * sv;
    }
    td = (td + 256.f * b_theta[tid]) * 0.08838834764831845f;
    pd = pd + 256.f * b_phi[tid];
    th_s[tid] = td;
    ph_s[tid] = pd;

    float pmax = pd, pmin = pd;
    for (int off = 32; off; off >>= 1) {
        pmax = fmaxf(pmax, __shfl_xor(pmax, off, 64));
        pmin = fminf(pmin, __shfl_xor(pmin, off, 64));
    }
    if ((tid & 63) == 0) { red2[tid >> 6] = pmax; red2[2 + (tid >> 6)] = pmin; }
    __syncthreads();
    const float gmax = fmaxf(red2[0], red2[1]);
    const float gmin = fminf(red2[2], red2[3]);

    const int wid = tid >> 6, lane = tid & 63;
    const float2 phv = *(const float2*)&ph_s[lane * 2];
    const float2 bg  = *(const float2*)&b_g[lane * 2];
#pragma unroll
    for (int cc = 0; cc < 8; ++cc) {
        const int c = part * 16 + wid * 8 + cc;
        const float thc = th_s[c];
        const float m = (thc >= 0.f) ? thc * gmax : thc * gmin;
        float e0 = __expf(thc * phv.x - m);
        float e1 = __expf(thc * phv.y - m);
        float z = e0 + e1;
        for (int off = 32; off; off >>= 1) z += __shfl_xor(z, off, 64);
        const float inv = 1.f / z;
        e0 *= inv; e1 *= inv;
        float2 av; av.x = e0; av.y = e1;
        *(float2*)&A[((size_t)n * CI + c) * CI + lane * 2] = av;
        float qv = e0 * bg.x + e1 * bg.y;
        for (int off = 32; off; off >>= 1) qv += __shfl_xor(qv, off, 64);
        if (lane == 0) q[n * CI + c] = qv;
    }
}

// ---------------------------------------------------------------------------
// K2: W_n[o,d] = sum_c w_out[o,c] A_n[c,d]; 8 o's/block, uniform weight loads.
// grid NB*32, block 128. Also cvec[n,o] = w_out[o,:].q_n + b_out[o].
__global__ __launch_bounds__(128) void k_W(const float* __restrict__ w_out,
        const float* __restrict__ A, const float* __restrict__ q,
        const float* __restrict__ b_out,
        float* __restrict__ W, float* __restrict__ cvec) {
    const int n = blockIdx.x >> 5, o0 = (blockIdx.x & 31) * 8, d = threadIdx.x;
    const float* Ab = A + (size_t)n * CI * CI + d;
    float acc[8] = {};
    for (int c = 0; c < CI; ++c) {
        const float av = Ab[(size_t)c * CI];
#pragma unroll
        for (int o = 0; o < 8; ++o) acc[o] += w_out[(o0 + o) * CI + c] * av;
    }
#pragma unroll
    for (int o = 0; o < 8; ++o) W[((size_t)n * C + o0 + o) * CI + d] = acc[o];
    __shared__ float red[8][2];
    const float qv = q[n * CI + d];
#pragma unroll
    for (int o = 0; o < 8; ++o) {
        float p = w_out[(o0 + o) * CI + d] * qv;
        for (int off = 32; off; off >>= 1) p += __shfl_down(p, off, 64);
        if ((d & 63) == 0) red[o][d >> 6] = p;
    }
    __syncthreads();
    if (d < 8) cvec[n * C + o0 + d] = red[d][0] + red[d][1] + b_out[o0 + d];
}

// ---------------------------------------------------------------------------
// K3: Mb16_n[o,c2] = bf16( sum_d W_n[o,d] w_g[d,c2] ); 8 o's/block.
// grid NB*32, block 256.
__global__ __launch_bounds__(256) void k_M(const float* __restrict__ W,
        const float* __restrict__ w_g, unsigned short* __restrict__ Mb16) {
    const int n = blockIdx.x >> 5, o0 = (blockIdx.x & 31) * 8, c2 = threadIdx.x;
    float acc[8] = {};
    for (int d = 0; d < CI; ++d) {
        const float wv = w_g[d * C + c2];
#pragma unroll
        for (int o = 0; o < 8; ++o)
            acc[o] += W[((size_t)n * C + o0 + o) * CI + d] * wv;
    }
#pragma unroll
    for (int o = 0; o < 8; ++o)
        Mb16[((size_t)n * C + o0 + o) * C + c2] = f2bf(acc[o]);
}

// ---------------------------------------------------------------------------
// K4: MFMA GEMM p[n] = M_n @ x[n] + cvec -> p bf16, with fused BN statistics
// (per-channel sum / sumsq via quad-reduce + atomicAdd). Store-only epilogue.
// grid (64, NB), block 256 (4 waves, 2x2 of 64x64).
__global__ __launch_bounds__(256) void k_gemm_stat(
        const unsigned short* __restrict__ xT,   // [n][4096][256] bf16
        const unsigned short* __restrict__ Mb,   // [n][256][256] bf16
        const float* __restrict__ cvec,
        unsigned short* __restrict__ pb,         // [n][256][4096] bf16
        float* __restrict__ mean_acc, float* __restrict__ e2_acc) {
    const int n  = blockIdx.y;
    const int tt = (blockIdx.x & 31) * 128;
    const int ot = (blockIdx.x >> 5) * 128;
    const int wave = threadIdx.x >> 6, lane = threadIdx.x & 63;
    const int wm = (wave >> 1) * 64, wn = (wave & 1) * 64;
    const int l15 = lane & 15, q8 = (lane >> 4) * 8;
    const unsigned short* Abase = Mb + ((size_t)n * C + ot + wm + l15) * C + q8;
    const unsigned short* Bbase = xT + ((size_t)n * HW + tt + wn + l15) * C + q8;
    floatx4 acc[4][4] = {};
    for (int k0 = 0; k0 < C; k0 += 32) {
        short8 a[4], b[4];
#pragma unroll
        for (int i = 0; i < 4; ++i)
            a[i] = *(const short8*)(Abase + (size_t)i * 16 * C + k0);
#pragma unroll
        for (int j = 0; j < 4; ++j)
            b[j] = *(const short8*)(Bbase + (size_t)j * 16 * C + k0);
#pragma unroll
        for (int i = 0; i < 4; ++i)
#pragma unroll
            for (int j = 0; j < 4; ++j)
                acc[i][j] = __builtin_amdgcn_mfma_f32_16x16x32_bf16(
                    a[i], b[j], acc[i][j], 0, 0, 0);
    }
    const int quad = lane >> 4;
#pragma unroll
    for (int i = 0; i < 4; ++i) {
        const int rowb = ot + wm + i * 16 + quad * 4;
#pragma unroll
        for (int r = 0; r < 4; ++r) {
            const int row = rowb + r;
            const float cv = cvec[n * C + row];
            unsigned short* prow = pb + ((size_t)n * C + row) * HW + tt + wn + l15;
            float v[4], s0 = 0.f, s1 = 0.f;
#pragma unroll
            for (int j = 0; j < 4; ++j) {
                v[j] = acc[i][j][r] + cv;
                s0 += v[j];
                s1 += v[j] * v[j];
            }
#pragma unroll
            for (int j = 0; j < 4; ++j) prow[j * 16] = f2bf(v[j]);
            // reduce across the 16 l15 lanes (xor of bits 0..3 stays in-quad)
            for (int off = 1; off < 16; off <<= 1) {
                s0 += __shfl_xor(s0, off, 64);
                s1 += __shfl_xor(s1, off, 64);
            }
            if (l15 == 0) {
                atomicAdd(&mean_acc[row], s0);
                atomicAdd(&e2_acc[row], s1);
            }
        }
    }
}

// ---------------------------------------------------------------------------
// K5: out = x + sc[c]*p + sh[c], sc/sh computed inline from the accumulators.
// grid 32768, block 256 (exactly one float4 per thread).
__global__ __launch_bounds__(256) void k_final(const float* __restrict__ x,
        const unsigned short* __restrict__ pb,
        const float* __restrict__ mean_acc, const float* __restrict__ e2_acc,
        const float* __restrict__ gamma, const float* __restrict__ beta,
        float* __restrict__ out) {
    const size_t i = (size_t)blockIdx.x * 256 + threadIdx.x;
    const int c = (int)((i >> 10) & 255);
    const float mean = mean_acc[c] * (1.f / FNHW);
    const float e2   = e2_acc[c] * (1.f / FNHW);
    const float var  = e2 - mean * mean;
    const float sc   = gamma[c] * rsqrtf(var + 1e-5f);
    const float sh   = beta[c] - mean * sc;
    const float4 xv = ((const float4*)x)[i];
    const uint2  pu = ((const uint2*)pb)[i];
    float4 r;
    r.x = xv.x + sc * __uint_as_float(pu.x << 16)          + sh;
    r.y = xv.y + sc * __uint_as_float(pu.x & 0xffff0000u)  + sh;
    r.z = xv.z + sc * __uint_as_float(pu.y << 16)          + sh;
    r.w = xv.w + sc * __uint_as_float(pu.y & 0xffff0000u)  + sh;
    ((float4*)out)[i] = r;
}

// ---------------------------------------------------------------------------
extern "C" void kernel_launch(void* const* d_in, const int* in_sizes, int n_in,
                              void* d_out, int out_size, void* d_ws, size_t ws_size,
                              hipStream_t stream) {
    const float* x       = (const float*)d_in[0];
    const float* w_theta = (const float*)d_in[1];
    const float* b_theta = (const float*)d_in[2];
    const float* w_phi   = (const float*)d_in[3];
    const float* b_phi   = (const float*)d_in[4];
    const float* w_g     = (const float*)d_in[5];
    const float* b_g     = (const float*)d_in[6];
    const float* w_out   = (const float*)d_in[7];
    const float* b_out   = (const float*)d_in[8];
    const float* gamma   = (const float*)d_in[9];
    const float* beta    = (const float*)d_in[10];
    float* out = (float*)d_out;
    float* ws  = (float*)d_ws;

    // workspace layout (float offsets); total ~140 MB
    float* s        = ws;                        // 8192
    float* mean_acc = s + NB * C;                // 256
    float* e2_acc   = mean_acc + C;              // 256  (zero region ends here)
    float* A        = e2_acc + C;                // 524288
    float* q        = A + (size_t)NB * CI * CI;  // 4096
    float* W        = q + NB * CI;               // 1048576
    float* cvec     = W + (size_t)NB * C * CI;   // 8192
    unsigned short* Mb16 = (unsigned short*)(cvec + NB * C);      // 4 MB
    unsigned short* xT   = Mb16 + (size_t)NB * C * C;             // 64 MB
    unsigned short* pb   = xT + (size_t)NB * HW * C;              // 64 MB

    hipMemsetAsync(s, 0, (NB * C + 2 * C) * sizeof(float), stream);
    k_prep<<<dim3(64, 4, NB), 256, 0, stream>>>(x, xT, s);
    k_attn<<<dim3(8, NB), 128, 0, stream>>>(s, w_theta, b_theta, w_phi, b_phi,
                                            b_g, A, q);
    k_W<<<NB * 32, CI, 0, stream>>>(w_out, A, q, b_out, W, cvec);
    k_M<<<NB * 32, C, 0, stream>>>(W, w_g, Mb16);
    k_gemm_stat<<<dim3(64, NB), 256, 0, stream>>>(xT, Mb16, cvec, pb,
                                                  mean_acc, e2_acc);
    k_final<<<32768, 256, 0, stream>>>(x, pb, mean_acc, e2_acc, gamma, beta, out);
}